// Round 6
// baseline (292.523 us; speedup 1.0000x reference)
//
#include <hip/hip_runtime.h>
#include <hip/hip_cooperative_groups.h>
#include <math.h>

#define F 128
#define FIX_SCALE 16777216.0f          // 2^24
#define FIX_INV   (1.0f / 16777216.0f)
#define CNT_SHIFT 40
#define DEG_MASK  ((1ULL << 40) - 1)
#define EVB 256                        // evolve blocks at front of count grid

using bf16x8 = __attribute__((ext_vector_type(8))) short;
using f32x4  = __attribute__((ext_vector_type(4))) float;

// ---------- helpers ----------
__device__ inline int read_idx(const int* ei, long long elem, int i64) {
    return i64 ? (int)((const long long*)ei)[elem] : ei[elem];
}
__device__ inline unsigned int f2bf_rn(float f) {   // fp32 -> bf16 bits, round-nearest-even
    unsigned int b = __float_as_uint(f);
    return (b + 0x7FFFu + ((b >> 16) & 1u)) >> 16;
}
__device__ inline float bflo(unsigned int u) { return __uint_as_float(u << 16); }
__device__ inline float bfhi(unsigned int u) { return __uint_as_float(u & 0xFFFF0000u); }

__device__ inline void acc8(float* acc, float wt, uint4 v) {
    acc[0] += wt * bflo(v.x); acc[1] += wt * bfhi(v.x);
    acc[2] += wt * bflo(v.y); acc[3] += wt * bfhi(v.y);
    acc[4] += wt * bflo(v.z); acc[5] += wt * bfhi(v.z);
    acc[6] += wt * bflo(v.w); acc[7] += wt * bfhi(v.w);
}

// per-block int64-dtype detection (replaces the flag kernel): the first 32
// column indices of an int64 edge_index have all-zero high words.
__device__ inline int detect_i64(const int* ei, int* sh) {
    if (threadIdx.x == 0) {
        int i64 = 1;
        for (int j = 0; j < 32; ++j) if (ei[2 * j + 1] != 0) { i64 = 0; break; }
        *sh = i64;
    }
    __syncthreads();
    return *sh;
}

// ---------- K1: GRU evolve (blocks [0,EVB)) + XCD-privatized count atomics (rest) ----------
// Evolve: split-K over 4 lane-groups (16 (i,j) pairs x 4 K-slices per wave), shuffle-reduce.
// Count: atomic into copy (blockIdx&7) -> line stays in home-XCD L2; pos = (copy<<24)|localpos.
__global__ __launch_bounds__(256) void k_count_evolve(
        const int* __restrict__ ei, const float* __restrict__ ew,
        unsigned long long* __restrict__ packed8, int* __restrict__ pos,
        int E, int N,
        const float* __restrict__ W0, const float* __restrict__ Wih,
        const float* __restrict__ Whh, const float* __restrict__ bih,
        const float* __restrict__ bhh,
        unsigned short* __restrict__ Wth, unsigned short* __restrict__ Wtl) {
    __shared__ int i64sh;
    int wave = threadIdx.x >> 6, lane = threadIdx.x & 63;
    if ((int)blockIdx.x >= EVB) {
        int i64 = detect_i64(ei, &i64sh);
        int e = ((int)blockIdx.x - EVB) * 256 + threadIdx.x;
        if (e >= E) return;
        int c = read_idx(ei, (long long)E + e, i64);
        int copy = blockIdx.x & 7;
        unsigned long long u = (1ULL << CNT_SHIFT) |
                               (unsigned long long)(ew[e] * FIX_SCALE + 0.5f);
        unsigned long long old = atomicAdd(&packed8[(size_t)copy * N + c], u);
        pos[e] = (int)(((unsigned int)(old >> CNT_SHIFT)) | ((unsigned int)copy << 24));
        return;
    }
    // ---- evolve: wave gw handles pairs [gw*16, gw*16+16), lane = (slice<<4)|lp ----
    int gw = (int)blockIdx.x * 4 + wave;          // 0..1023
    int pairBase = gw * 16;
    int i = pairBase >> 7;                        // row of W0
    int jb = pairBase & 127;
    int lp = lane & 15, sl = lane >> 4;           // pair-in-wave, K-slice
    int j = jb + lp;                              // col of W
    const float* w0p = W0 + (size_t)i * F;
    const float* pir = Wih + (size_t)j * F;
    const float* piz = Wih + (size_t)(j + F) * F;
    const float* pin = Wih + (size_t)(j + 2 * F) * F;
    const float* phr = Whh + (size_t)j * F;
    const float* phz = Whh + (size_t)(j + F) * F;
    const float* phn = Whh + (size_t)(j + 2 * F) * F;
    float air = 0, aiz = 0, ain = 0, ahr = 0, ahz = 0, ahn = 0;
    int k0 = sl * 32;
    #pragma unroll
    for (int kk = 0; kk < 32; kk += 4) {
        int k = k0 + kk;
        float4 w0 = *(const float4*)&w0p[k];
        float4 a;
        a = *(const float4*)&pir[k]; air += w0.x*a.x + w0.y*a.y + w0.z*a.z + w0.w*a.w;
        a = *(const float4*)&piz[k]; aiz += w0.x*a.x + w0.y*a.y + w0.z*a.z + w0.w*a.w;
        a = *(const float4*)&pin[k]; ain += w0.x*a.x + w0.y*a.y + w0.z*a.z + w0.w*a.w;
        a = *(const float4*)&phr[k]; ahr += w0.x*a.x + w0.y*a.y + w0.z*a.z + w0.w*a.w;
        a = *(const float4*)&phz[k]; ahz += w0.x*a.x + w0.y*a.y + w0.z*a.z + w0.w*a.w;
        a = *(const float4*)&phn[k]; ahn += w0.x*a.x + w0.y*a.y + w0.z*a.z + w0.w*a.w;
    }
    air += __shfl_xor(air, 16, 64); air += __shfl_xor(air, 32, 64);
    aiz += __shfl_xor(aiz, 16, 64); aiz += __shfl_xor(aiz, 32, 64);
    ain += __shfl_xor(ain, 16, 64); ain += __shfl_xor(ain, 32, 64);
    ahr += __shfl_xor(ahr, 16, 64); ahr += __shfl_xor(ahr, 32, 64);
    ahz += __shfl_xor(ahz, 16, 64); ahz += __shfl_xor(ahz, 32, 64);
    ahn += __shfl_xor(ahn, 16, 64); ahn += __shfl_xor(ahn, 32, 64);
    if (sl == 0) {
        air += bih[j];          ahr += bhh[j];
        aiz += bih[j + F];      ahz += bhh[j + F];
        ain += bih[j + 2 * F];  ahn += bhh[j + 2 * F];
        float r = 1.0f / (1.0f + expf(-(air + ahr)));
        float z = 1.0f / (1.0f + expf(-(aiz + ahz)));
        float n = tanhf(ain + r * ahn);
        float w = (1.0f - z) * n + z * w0p[j];
        unsigned int hb = f2bf_rn(w);
        float whi = __uint_as_float(hb << 16);
        unsigned int lb = f2bf_rn(w - whi);
        Wth[j * F + i] = (unsigned short)hb;
        Wtl[j * F + i] = (unsigned short)lb;
    }
}

// ---------- K2 (cooperative): fused bsum + bscan + offs ----------
// Per-node state (cb[8], v, dsum, incl) lives in registers across grid.sync().
__global__ __launch_bounds__(256) void k_scan(const unsigned long long* __restrict__ packed8,
        int* __restrict__ bsum, int* __restrict__ off, int* __restrict__ copyBase,
        float* __restrict__ dinv, int N, int E, int nblk) {
    cooperative_groups::grid_group grid = cooperative_groups::this_grid();
    __shared__ int sdata[256];
    int t = threadIdx.x, b = blockIdx.x;
    int i = b * 256 + t;
    int v = 0;
    unsigned long long dsum = 0;
    if (i < N) {
        int run = 0;
        int cb[8];
        #pragma unroll
        for (int k = 0; k < 8; ++k) {
            unsigned long long p = packed8[(size_t)k * N + i];
            cb[k] = run;
            run += (int)(p >> CNT_SHIFT);
            dsum += (p & DEG_MASK);
        }
        v = run;
        #pragma unroll
        for (int k = 0; k < 8; ++k) copyBase[(size_t)i * 8 + k] = cb[k];
    }
    sdata[t] = v;
    __syncthreads();
    #pragma unroll
    for (int s = 1; s < 256; s <<= 1) {
        int add = (t >= s) ? sdata[t - s] : 0;
        __syncthreads();
        sdata[t] += add;
        __syncthreads();
    }
    int incl = sdata[t];
    if (t == 255) bsum[b] = incl;
    __threadfence();
    grid.sync();
    if (b == 0) {           // exclusive scan of block sums (nblk=196 -> 1 pass)
        int run = 0;
        for (int base = 0; base < nblk; base += 256) {
            int idx = base + t;
            int bv = (idx < nblk) ? bsum[idx] : 0;
            __syncthreads();
            sdata[t] = bv;
            __syncthreads();
            #pragma unroll
            for (int s = 1; s < 256; s <<= 1) {
                int add = (t >= s) ? sdata[t - s] : 0;
                __syncthreads();
                sdata[t] += add;
                __syncthreads();
            }
            if (idx < nblk) bsum[idx] = run + sdata[t] - bv;
            run += sdata[255];
            __syncthreads();
        }
        __threadfence();
    }
    grid.sync();
    if (i < N) {
        off[i] = bsum[b] + incl - v;  // exclusive CSR offset
        dinv[i] = rsqrtf(1.0f + (float)dsum * FIX_INV);  // +1 self-loop
        if (i == N - 1) off[N] = E;
    }
}

// ---------- K3: edge placement (blocks [0,placeBlocks)) + xs cast (rest) ----------
__global__ __launch_bounds__(256) void k_place_cast(
        const int* __restrict__ ei, const float* __restrict__ ew,
        const int* __restrict__ off, const int* __restrict__ copyBase,
        const int* __restrict__ pos,
        int2* __restrict__ ep, int E, int placeBlocks,
        const float2* __restrict__ x2, const float* __restrict__ dinv,
        unsigned int* __restrict__ xs, int M) {
    __shared__ int i64sh;
    if ((int)blockIdx.x < placeBlocks) {
        int i64 = detect_i64(ei, &i64sh);
        int e = blockIdx.x * 256 + threadIdx.x;
        if (e >= E) return;
        int r = read_idx(ei, e, i64);
        int c = read_idx(ei, (long long)E + e, i64);
        int pe = pos[e];
        int slot = off[c] + copyBase[(size_t)c * 8 + ((unsigned int)pe >> 24)] + (pe & 0xFFFFFF);
        ep[slot] = make_int2(r, __float_as_int(ew[e]));
    } else {
        int id = ((int)blockIdx.x - placeBlocks) * 256 + threadIdx.x;
        if (id >= M) return;
        float di = dinv[id >> 6];
        float2 v = x2[id];
        xs[id] = f2bf_rn(di * v.x) | (f2bf_rn(di * v.y) << 16);
    }
}

// ---------- K4: aggregation: hagg[c] = bf16( dinv[c] * (xs[c] + sum ew*xs[r]) ) ----------
// One node per wave; 16 edges/iteration (4 per 16-lane group), branchless tail via
// index clamp + zero weight so all 4 gathers issue unconditionally (deep MLP).
__global__ __launch_bounds__(256) void k_agg2(const uint4* __restrict__ xs4,
                                              const int* __restrict__ off,
                                              const int2* __restrict__ ep,
                                              const float* __restrict__ dinv,
                                              uint4* __restrict__ hagg4, int N) {
    int wave = threadIdx.x >> 6, lane = threadIdx.x & 63;
    int c = blockIdx.x * 4 + wave;
    if (c >= N) return;
    int g = lane >> 4, sl = lane & 15;
    int start = off[c], end = off[c + 1];
    float di = dinv[c];
    float a0[8] = {0,0,0,0,0,0,0,0}, a1[8] = {0,0,0,0,0,0,0,0};
    if (g == 0) {   // self-loop (raw weight 1)
        uint4 v = xs4[(size_t)c * 16 + sl];
        a0[0] = bflo(v.x); a0[1] = bfhi(v.x);
        a0[2] = bflo(v.y); a0[3] = bfhi(v.y);
        a0[4] = bflo(v.z); a0[5] = bfhi(v.z);
        a0[6] = bflo(v.w); a0[7] = bfhi(v.w);
    }
    int last = end - 1;
    for (int k = start; k < end; k += 16) {
        int iA = k + g, iB = k + g + 4, iC = k + g + 8, iD = k + g + 12;
        int2 eA = ep[min(iA, last)];
        int2 eB = ep[min(iB, last)];
        int2 eC = ep[min(iC, last)];
        int2 eD = ep[min(iD, last)];
        uint4 vA = xs4[(size_t)eA.x * 16 + sl];
        uint4 vB = xs4[(size_t)eB.x * 16 + sl];
        uint4 vC = xs4[(size_t)eC.x * 16 + sl];
        uint4 vD = xs4[(size_t)eD.x * 16 + sl];
        float wA = (iA <= last) ? __int_as_float(eA.y) : 0.f;
        float wB = (iB <= last) ? __int_as_float(eB.y) : 0.f;
        float wC = (iC <= last) ? __int_as_float(eC.y) : 0.f;
        float wD = (iD <= last) ? __int_as_float(eD.y) : 0.f;
        acc8(a0, wA, vA);
        acc8(a1, wB, vB);
        acc8(a0, wC, vC);
        acc8(a1, wD, vD);
    }
    #pragma unroll
    for (int f = 0; f < 8; ++f) {
        float v = a0[f] + a1[f];
        v += __shfl_xor(v, 16, 64);
        v += __shfl_xor(v, 32, 64);
        a0[f] = v;
    }
    if (lane < 16) {
        uint4 o;
        o.x = f2bf_rn(di * a0[0]) | (f2bf_rn(di * a0[1]) << 16);
        o.y = f2bf_rn(di * a0[2]) | (f2bf_rn(di * a0[3]) << 16);
        o.z = f2bf_rn(di * a0[4]) | (f2bf_rn(di * a0[5]) << 16);
        o.w = f2bf_rn(di * a0[6]) | (f2bf_rn(di * a0[7]) << 16);
        hagg4[(size_t)c * 16 + lane] = o;
    }
}

// ---------- K5: out = relu(hagg @ W) @ Wlin^T + blin  (MFMA, split-bf16 W) ----------
__global__ __launch_bounds__(256) void k_gemm(const uint4* __restrict__ hagg4,
                                              const unsigned short* __restrict__ Wth,
                                              const unsigned short* __restrict__ Wtl,
                                              const float* __restrict__ Wlin,
                                              const float* __restrict__ blin,
                                              float* __restrict__ out, int N) {
    __shared__ __align__(16) unsigned int At[64 * 68];  // 64 rows bf16x128, stride padded 68 uints
    __shared__ __align__(16) float WlinL[8 * F];
    int t = threadIdx.x;
    int row0 = blockIdx.x * 64;
    #pragma unroll
    for (int it = 0; it < 4; ++it) {
        int idx = it * 256 + t;          // 1024 uint4 slots
        int rr = idx >> 4, c4 = idx & 15;
        uint4 v = make_uint4(0u, 0u, 0u, 0u);
        if (row0 + rr < N) v = hagg4[(size_t)(row0 + rr) * 16 + c4];
        *(uint4*)&At[rr * 68 + c4 * 4] = v;
    }
    *(float4*)&WlinL[t * 4] = *(const float4*)&Wlin[t * 4];   // 1024 floats
    __syncthreads();

    int wave = t >> 6, lane = t & 63;
    int sl = lane & 15, q = lane >> 4;
    const unsigned short* Ash = (const unsigned short*)At;
    int mrow = wave * 16 + sl;           // A-row within tile (m = lane&15)

    f32x4 acc[8];
    #pragma unroll
    for (int nt = 0; nt < 8; ++nt) acc[nt] = (f32x4){0.f, 0.f, 0.f, 0.f};
    #pragma unroll
    for (int ko = 0; ko < 4; ++ko) {
        bf16x8 a = *(const bf16x8*)&Ash[mrow * 136 + ko * 32 + q * 8];
        #pragma unroll
        for (int nt = 0; nt < 8; ++nt) {
            int boff = (nt * 16 + sl) * F + ko * 32 + q * 8;
            bf16x8 bh = *(const bf16x8*)&Wth[boff];
            bf16x8 bl = *(const bf16x8*)&Wtl[boff];
            acc[nt] = __builtin_amdgcn_mfma_f32_16x16x32_bf16(a, bh, acc[nt], 0, 0, 0);
            acc[nt] = __builtin_amdgcn_mfma_f32_16x16x32_bf16(a, bl, acc[nt], 0, 0, 0);
        }
    }
    // relu (C layout: row = q*4+reg, col = nt*16+sl)
    #pragma unroll
    for (int nt = 0; nt < 8; ++nt)
        #pragma unroll
        for (int r = 0; r < 4; ++r) acc[nt][r] = fmaxf(acc[nt][r], 0.f);

    // fp32 projection: p[t][reg] = sum_col relu(S)[row][col] * Wlin[t][col]
    float p[8][4];
    #pragma unroll
    for (int tt = 0; tt < 8; ++tt) {
        float wl[8];
        #pragma unroll
        for (int nt = 0; nt < 8; ++nt) wl[nt] = WlinL[tt * F + nt * 16 + sl];
        #pragma unroll
        for (int r = 0; r < 4; ++r) {
            float s = 0.f;
            #pragma unroll
            for (int nt = 0; nt < 8; ++nt) s += acc[nt][r] * wl[nt];
            p[tt][r] = s;
        }
    }
    #pragma unroll
    for (int tt = 0; tt < 8; ++tt)
        #pragma unroll
        for (int r = 0; r < 4; ++r) {
            float v = p[tt][r];
            v += __shfl_xor(v, 1, 64); v += __shfl_xor(v, 2, 64);
            v += __shfl_xor(v, 4, 64); v += __shfl_xor(v, 8, 64);
            p[tt][r] = v;
        }
    if (sl == 0) {
        #pragma unroll
        for (int r = 0; r < 4; ++r) {
            int row = row0 + wave * 16 + q * 4 + r;
            if (row < N) {
                #pragma unroll
                for (int tt = 0; tt < 8; ++tt)
                    out[(size_t)row * 8 + tt] = p[tt][r] + blin[tt];
            }
        }
    }
}

// ---------- launch ----------
extern "C" void kernel_launch(void* const* d_in, const int* in_sizes, int n_in,
                              void* d_out, int out_size, void* d_ws, size_t ws_size,
                              hipStream_t stream) {
    const float* x    = (const float*)d_in[0];
    const int*   ei   = (const int*)d_in[1];
    const float* ew   = (const float*)d_in[2];
    const float* W0   = (const float*)d_in[3];
    const float* Wih  = (const float*)d_in[4];
    const float* Whh  = (const float*)d_in[5];
    const float* bih  = (const float*)d_in[6];
    const float* bhh  = (const float*)d_in[7];
    const float* Wlin = (const float*)d_in[8];
    const float* blin = (const float*)d_in[9];
    int N = in_sizes[0] / F;   // 50000
    int E = in_sizes[1] / 2;   // 800000
    float* outp = (float*)d_out;

    int nblk = (N + 255) / 256;
    int cntBlocks = (E + 255) / 256;
    int M = N * 64;
    int M8 = N * 8;

    char* wsb = (char*)d_ws;
    size_t cur = 0;
    auto alloc = [&](size_t sz) -> void* {
        void* p = wsb + cur;
        cur = (cur + sz + 255) & ~(size_t)255;
        return p;
    };
    unsigned long long* packed8 = (unsigned long long*)alloc((size_t)M8 * 8);
    float* dinv = (float*)alloc((size_t)N * 4);
    int*   off  = (int*)  alloc((size_t)(N + 1) * 4);
    int*   bsum = (int*)  alloc((size_t)nblk * 4);
    int*   pos  = (int*)  alloc((size_t)E * 4);
    int*   copyBase = (int*)alloc((size_t)N * 8 * 4);
    int2*  ep   = (int2*) alloc((size_t)E * 8);
    unsigned short* Wth = (unsigned short*)alloc((size_t)F * F * 2);
    unsigned short* Wtl = (unsigned short*)alloc((size_t)F * F * 2);
    unsigned int* xs    = (unsigned int*)alloc((size_t)N * 64 * 4);
    unsigned int* hagg  = (unsigned int*)alloc((size_t)N * 64 * 4);
    (void)ws_size; (void)n_in; (void)out_size;

    hipMemsetAsync(packed8, 0, (size_t)M8 * 8, stream);
    hipLaunchKernelGGL(k_count_evolve, dim3(EVB + cntBlocks), dim3(256), 0, stream,
                       ei, ew, packed8, pos, E, N,
                       W0, Wih, Whh, bih, bhh, Wth, Wtl);
    {
        void* args[] = { (void*)&packed8, (void*)&bsum, (void*)&off, (void*)&copyBase,
                         (void*)&dinv, (void*)&N, (void*)&E, (void*)&nblk };
        hipLaunchCooperativeKernel((void*)k_scan, dim3(nblk), dim3(256), args, 0, stream);
    }
    hipLaunchKernelGGL(k_place_cast, dim3(cntBlocks + (M + 255) / 256), dim3(256), 0, stream,
                       ei, ew, off, copyBase, pos, ep, E, cntBlocks,
                       (const float2*)x, dinv, xs, M);
    hipLaunchKernelGGL(k_agg2, dim3((N + 3) / 4), dim3(256), 0, stream,
                       (const uint4*)xs, off, ep, dinv, (uint4*)hagg, N);
    hipLaunchKernelGGL(k_gemm, dim3((N + 63) / 64), dim3(256), 0, stream,
                       (const uint4*)hagg, Wth, Wtl, Wlin, blin, outp, N);
}

// Round 7
// 217.842 us; speedup vs baseline: 1.3428x; 1.3428x over previous
//
#include <hip/hip_runtime.h>
#include <math.h>

#define F 128
#define FIX_SCALE 16777216.0f          // 2^24
#define FIX_INV   (1.0f / 16777216.0f)
#define CNT_SHIFT 40
#define DEG_MASK  ((1ULL << 40) - 1)
#define EVB 256                        // evolve blocks at front of count grid

using bf16x8 = __attribute__((ext_vector_type(8))) short;
using f32x4  = __attribute__((ext_vector_type(4))) float;

// ---------- helpers ----------
__device__ inline int read_idx(const int* ei, long long elem, int i64) {
    return i64 ? (int)((const long long*)ei)[elem] : ei[elem];
}
__device__ inline unsigned int f2bf_rn(float f) {   // fp32 -> bf16 bits, round-nearest-even
    unsigned int b = __float_as_uint(f);
    return (b + 0x7FFFu + ((b >> 16) & 1u)) >> 16;
}
__device__ inline float bflo(unsigned int u) { return __uint_as_float(u << 16); }
__device__ inline float bfhi(unsigned int u) { return __uint_as_float(u & 0xFFFF0000u); }

__device__ inline void acc8(float* acc, float wt, uint4 v) {
    acc[0] += wt * bflo(v.x); acc[1] += wt * bfhi(v.x);
    acc[2] += wt * bflo(v.y); acc[3] += wt * bfhi(v.y);
    acc[4] += wt * bflo(v.z); acc[5] += wt * bfhi(v.z);
    acc[6] += wt * bflo(v.w); acc[7] += wt * bfhi(v.w);
}

// per-block int64-dtype detection (no flag kernel): the first 32 column
// indices of an int64 edge_index have all-zero high words.
__device__ inline int detect_i64(const int* ei, int* sh) {
    if (threadIdx.x == 0) {
        int i64 = 1;
        for (int j = 0; j < 32; ++j) if (ei[2 * j + 1] != 0) { i64 = 0; break; }
        *sh = i64;
    }
    __syncthreads();
    return *sh;
}

// ---------- K1: GRU evolve (blocks [0,EVB)) + XCD-privatized count atomics (rest) ----------
// Evolve: split-K over 4 lane-groups (16 (i,j) pairs x 4 K-slices per wave), shuffle-reduce.
// Count: atomic into copy (blockIdx&7) -> line stays in home-XCD L2; pos = (copy<<24)|localpos.
__global__ __launch_bounds__(256) void k_count_evolve(
        const int* __restrict__ ei, const float* __restrict__ ew,
        unsigned long long* __restrict__ packed8, int* __restrict__ pos,
        int E, int N,
        const float* __restrict__ W0, const float* __restrict__ Wih,
        const float* __restrict__ Whh, const float* __restrict__ bih,
        const float* __restrict__ bhh,
        unsigned short* __restrict__ Wth, unsigned short* __restrict__ Wtl) {
    __shared__ int i64sh;
    int wave = threadIdx.x >> 6, lane = threadIdx.x & 63;
    if ((int)blockIdx.x >= EVB) {
        int i64 = detect_i64(ei, &i64sh);
        int e = ((int)blockIdx.x - EVB) * 256 + threadIdx.x;
        if (e >= E) return;
        int c = read_idx(ei, (long long)E + e, i64);
        int copy = blockIdx.x & 7;
        unsigned long long u = (1ULL << CNT_SHIFT) |
                               (unsigned long long)(ew[e] * FIX_SCALE + 0.5f);
        unsigned long long old = atomicAdd(&packed8[(size_t)copy * N + c], u);
        pos[e] = (int)(((unsigned int)(old >> CNT_SHIFT)) | ((unsigned int)copy << 24));
        return;
    }
    // ---- evolve: wave gw handles pairs [gw*16, gw*16+16), lane = (slice<<4)|lp ----
    int gw = (int)blockIdx.x * 4 + wave;          // 0..1023
    int pairBase = gw * 16;
    int i = pairBase >> 7;                        // row of W0
    int jb = pairBase & 127;
    int lp = lane & 15, sl = lane >> 4;           // pair-in-wave, K-slice
    int j = jb + lp;                              // col of W
    const float* w0p = W0 + (size_t)i * F;
    const float* pir = Wih + (size_t)j * F;
    const float* piz = Wih + (size_t)(j + F) * F;
    const float* pin = Wih + (size_t)(j + 2 * F) * F;
    const float* phr = Whh + (size_t)j * F;
    const float* phz = Whh + (size_t)(j + F) * F;
    const float* phn = Whh + (size_t)(j + 2 * F) * F;
    float air = 0, aiz = 0, ain = 0, ahr = 0, ahz = 0, ahn = 0;
    int k0 = sl * 32;
    #pragma unroll
    for (int kk = 0; kk < 32; kk += 4) {
        int k = k0 + kk;
        float4 w0 = *(const float4*)&w0p[k];
        float4 a;
        a = *(const float4*)&pir[k]; air += w0.x*a.x + w0.y*a.y + w0.z*a.z + w0.w*a.w;
        a = *(const float4*)&piz[k]; aiz += w0.x*a.x + w0.y*a.y + w0.z*a.z + w0.w*a.w;
        a = *(const float4*)&pin[k]; ain += w0.x*a.x + w0.y*a.y + w0.z*a.z + w0.w*a.w;
        a = *(const float4*)&phr[k]; ahr += w0.x*a.x + w0.y*a.y + w0.z*a.z + w0.w*a.w;
        a = *(const float4*)&phz[k]; ahz += w0.x*a.x + w0.y*a.y + w0.z*a.z + w0.w*a.w;
        a = *(const float4*)&phn[k]; ahn += w0.x*a.x + w0.y*a.y + w0.z*a.z + w0.w*a.w;
    }
    air += __shfl_xor(air, 16, 64); air += __shfl_xor(air, 32, 64);
    aiz += __shfl_xor(aiz, 16, 64); aiz += __shfl_xor(aiz, 32, 64);
    ain += __shfl_xor(ain, 16, 64); ain += __shfl_xor(ain, 32, 64);
    ahr += __shfl_xor(ahr, 16, 64); ahr += __shfl_xor(ahr, 32, 64);
    ahz += __shfl_xor(ahz, 16, 64); ahz += __shfl_xor(ahz, 32, 64);
    ahn += __shfl_xor(ahn, 16, 64); ahn += __shfl_xor(ahn, 32, 64);
    if (sl == 0) {
        air += bih[j];          ahr += bhh[j];
        aiz += bih[j + F];      ahz += bhh[j + F];
        ain += bih[j + 2 * F];  ahn += bhh[j + 2 * F];
        float r = 1.0f / (1.0f + expf(-(air + ahr)));
        float z = 1.0f / (1.0f + expf(-(aiz + ahz)));
        float n = tanhf(ain + r * ahn);
        float w = (1.0f - z) * n + z * w0p[j];
        unsigned int hb = f2bf_rn(w);
        float whi = __uint_as_float(hb << 16);
        unsigned int lb = f2bf_rn(w - whi);
        Wth[j * F + i] = (unsigned short)hb;
        Wtl[j * F + i] = (unsigned short)lb;
    }
}

// ---------- K2: per-block sums of cnt (summed over 8 copies) ----------
__global__ void k_bsum(const unsigned long long* __restrict__ packed8,
                       int* __restrict__ bsum, int N) {
    __shared__ int s[4];
    int i = blockIdx.x * 256 + threadIdx.x;
    int v = 0;
    if (i < N) {
        #pragma unroll
        for (int k = 0; k < 8; ++k)
            v += (int)(packed8[(size_t)k * N + i] >> CNT_SHIFT);
    }
    #pragma unroll
    for (int o = 1; o < 64; o <<= 1) v += __shfl_xor(v, o, 64);
    if ((threadIdx.x & 63) == 0) s[threadIdx.x >> 6] = v;
    __syncthreads();
    if (threadIdx.x == 0) bsum[blockIdx.x] = s[0] + s[1] + s[2] + s[3];
}

// ---------- K3: offs (each block self-scans bsum -> no separate bscan kernel) ----------
// nblk ~196: each block reduces bsum[idx<b] locally (L2-hit), then block-local scan.
__global__ void k_offs(const unsigned long long* __restrict__ packed8,
                       const int* __restrict__ bsum,
                       int* __restrict__ off, int* __restrict__ copyBase,
                       float* __restrict__ dinv, int N, int E, int nblk) {
    __shared__ int sdata[256];
    __shared__ int sred[4];
    __shared__ int sbase;
    int t = threadIdx.x;
    int b = blockIdx.x;
    // blockBase = sum of bsum[0..b)
    int base = 0;
    for (int s0 = 0; s0 < nblk; s0 += 256) {
        int idx = s0 + t;
        int v = (idx < nblk && idx < b) ? bsum[idx] : 0;
        #pragma unroll
        for (int o = 1; o < 64; o <<= 1) v += __shfl_xor(v, o, 64);
        if ((t & 63) == 0) sred[t >> 6] = v;
        __syncthreads();
        if (t == 0) sbase = sred[0] + sred[1] + sred[2] + sred[3];
        __syncthreads();
        base += sbase;
        __syncthreads();
    }
    // per-node: copy bases, degree, block-local exclusive scan
    int i = b * 256 + t;
    int v = 0;
    unsigned long long dsum = 0;
    if (i < N) {
        int run = 0;
        int cb[8];
        #pragma unroll
        for (int k = 0; k < 8; ++k) {
            unsigned long long p = packed8[(size_t)k * N + i];
            cb[k] = run;
            run += (int)(p >> CNT_SHIFT);
            dsum += (p & DEG_MASK);
        }
        v = run;
        #pragma unroll
        for (int k = 0; k < 8; ++k) copyBase[(size_t)i * 8 + k] = cb[k];
    }
    sdata[t] = v;
    __syncthreads();
    #pragma unroll
    for (int s = 1; s < 256; s <<= 1) {
        int add = (t >= s) ? sdata[t - s] : 0;
        __syncthreads();
        sdata[t] += add;
        __syncthreads();
    }
    if (i < N) {
        off[i] = base + sdata[t] - v;  // exclusive CSR offset
        dinv[i] = rsqrtf(1.0f + (float)dsum * FIX_INV);  // +1 self-loop
        if (i == N - 1) off[N] = E;
    }
}

// ---------- K4: edge placement (blocks [0,placeBlocks)) + xs cast (rest) ----------
__global__ __launch_bounds__(256) void k_place_cast(
        const int* __restrict__ ei, const float* __restrict__ ew,
        const int* __restrict__ off, const int* __restrict__ copyBase,
        const int* __restrict__ pos,
        int2* __restrict__ ep, int E, int placeBlocks,
        const float2* __restrict__ x2, const float* __restrict__ dinv,
        unsigned int* __restrict__ xs, int M) {
    __shared__ int i64sh;
    if ((int)blockIdx.x < placeBlocks) {
        int i64 = detect_i64(ei, &i64sh);
        int e = blockIdx.x * 256 + threadIdx.x;
        if (e >= E) return;
        int r = read_idx(ei, e, i64);
        int c = read_idx(ei, (long long)E + e, i64);
        int pe = pos[e];
        int slot = off[c] + copyBase[(size_t)c * 8 + ((unsigned int)pe >> 24)] + (pe & 0xFFFFFF);
        ep[slot] = make_int2(r, __float_as_int(ew[e]));
    } else {
        int id = ((int)blockIdx.x - placeBlocks) * 256 + threadIdx.x;
        if (id >= M) return;
        float di = dinv[id >> 6];
        float2 v = x2[id];
        xs[id] = f2bf_rn(di * v.x) | (f2bf_rn(di * v.y) << 16);
    }
}

// ---------- K5: aggregation: hagg[c] = bf16( dinv[c] * (xs[c] + sum ew*xs[r]) ) ----------
// One node per wave; 16 edges/iteration (4 per 16-lane group), branchless tail via
// index clamp + zero weight so all 4 gathers issue unconditionally (deep MLP).
__global__ __launch_bounds__(256) void k_agg2(const uint4* __restrict__ xs4,
                                              const int* __restrict__ off,
                                              const int2* __restrict__ ep,
                                              const float* __restrict__ dinv,
                                              uint4* __restrict__ hagg4, int N) {
    int wave = threadIdx.x >> 6, lane = threadIdx.x & 63;
    int c = blockIdx.x * 4 + wave;
    if (c >= N) return;
    int g = lane >> 4, sl = lane & 15;
    int start = off[c], end = off[c + 1];
    float di = dinv[c];
    float a0[8] = {0,0,0,0,0,0,0,0}, a1[8] = {0,0,0,0,0,0,0,0};
    if (g == 0) {   // self-loop (raw weight 1)
        uint4 v = xs4[(size_t)c * 16 + sl];
        a0[0] = bflo(v.x); a0[1] = bfhi(v.x);
        a0[2] = bflo(v.y); a0[3] = bfhi(v.y);
        a0[4] = bflo(v.z); a0[5] = bfhi(v.z);
        a0[6] = bflo(v.w); a0[7] = bfhi(v.w);
    }
    int last = end - 1;
    for (int k = start; k < end; k += 16) {
        int iA = k + g, iB = k + g + 4, iC = k + g + 8, iD = k + g + 12;
        int2 eA = ep[min(iA, last)];
        int2 eB = ep[min(iB, last)];
        int2 eC = ep[min(iC, last)];
        int2 eD = ep[min(iD, last)];
        uint4 vA = xs4[(size_t)eA.x * 16 + sl];
        uint4 vB = xs4[(size_t)eB.x * 16 + sl];
        uint4 vC = xs4[(size_t)eC.x * 16 + sl];
        uint4 vD = xs4[(size_t)eD.x * 16 + sl];
        float wA = (iA <= last) ? __int_as_float(eA.y) : 0.f;
        float wB = (iB <= last) ? __int_as_float(eB.y) : 0.f;
        float wC = (iC <= last) ? __int_as_float(eC.y) : 0.f;
        float wD = (iD <= last) ? __int_as_float(eD.y) : 0.f;
        acc8(a0, wA, vA);
        acc8(a1, wB, vB);
        acc8(a0, wC, vC);
        acc8(a1, wD, vD);
    }
    #pragma unroll
    for (int f = 0; f < 8; ++f) {
        float v = a0[f] + a1[f];
        v += __shfl_xor(v, 16, 64);
        v += __shfl_xor(v, 32, 64);
        a0[f] = v;
    }
    if (lane < 16) {
        uint4 o;
        o.x = f2bf_rn(di * a0[0]) | (f2bf_rn(di * a0[1]) << 16);
        o.y = f2bf_rn(di * a0[2]) | (f2bf_rn(di * a0[3]) << 16);
        o.z = f2bf_rn(di * a0[4]) | (f2bf_rn(di * a0[5]) << 16);
        o.w = f2bf_rn(di * a0[6]) | (f2bf_rn(di * a0[7]) << 16);
        hagg4[(size_t)c * 16 + lane] = o;
    }
}

// ---------- K6: out = relu(hagg @ W) @ Wlin^T + blin  (MFMA, split-bf16 W) ----------
__global__ __launch_bounds__(256) void k_gemm(const uint4* __restrict__ hagg4,
                                              const unsigned short* __restrict__ Wth,
                                              const unsigned short* __restrict__ Wtl,
                                              const float* __restrict__ Wlin,
                                              const float* __restrict__ blin,
                                              float* __restrict__ out, int N) {
    __shared__ __align__(16) unsigned int At[64 * 68];  // 64 rows bf16x128, stride padded 68 uints
    __shared__ __align__(16) float WlinL[8 * F];
    int t = threadIdx.x;
    int row0 = blockIdx.x * 64;
    #pragma unroll
    for (int it = 0; it < 4; ++it) {
        int idx = it * 256 + t;          // 1024 uint4 slots
        int rr = idx >> 4, c4 = idx & 15;
        uint4 v = make_uint4(0u, 0u, 0u, 0u);
        if (row0 + rr < N) v = hagg4[(size_t)(row0 + rr) * 16 + c4];
        *(uint4*)&At[rr * 68 + c4 * 4] = v;
    }
    *(float4*)&WlinL[t * 4] = *(const float4*)&Wlin[t * 4];   // 1024 floats
    __syncthreads();

    int wave = t >> 6, lane = t & 63;
    int sl = lane & 15, q = lane >> 4;
    const unsigned short* Ash = (const unsigned short*)At;
    int mrow = wave * 16 + sl;           // A-row within tile (m = lane&15)

    f32x4 acc[8];
    #pragma unroll
    for (int nt = 0; nt < 8; ++nt) acc[nt] = (f32x4){0.f, 0.f, 0.f, 0.f};
    #pragma unroll
    for (int ko = 0; ko < 4; ++ko) {
        bf16x8 a = *(const bf16x8*)&Ash[mrow * 136 + ko * 32 + q * 8];
        #pragma unroll
        for (int nt = 0; nt < 8; ++nt) {
            int boff = (nt * 16 + sl) * F + ko * 32 + q * 8;
            bf16x8 bh = *(const bf16x8*)&Wth[boff];
            bf16x8 bl = *(const bf16x8*)&Wtl[boff];
            acc[nt] = __builtin_amdgcn_mfma_f32_16x16x32_bf16(a, bh, acc[nt], 0, 0, 0);
            acc[nt] = __builtin_amdgcn_mfma_f32_16x16x32_bf16(a, bl, acc[nt], 0, 0, 0);
        }
    }
    // relu (C layout: row = q*4+reg, col = nt*16+sl)
    #pragma unroll
    for (int nt = 0; nt < 8; ++nt)
        #pragma unroll
        for (int r = 0; r < 4; ++r) acc[nt][r] = fmaxf(acc[nt][r], 0.f);

    // fp32 projection: p[t][reg] = sum_col relu(S)[row][col] * Wlin[t][col]
    float p[8][4];
    #pragma unroll
    for (int tt = 0; tt < 8; ++tt) {
        float wl[8];
        #pragma unroll
        for (int nt = 0; nt < 8; ++nt) wl[nt] = WlinL[tt * F + nt * 16 + sl];
        #pragma unroll
        for (int r = 0; r < 4; ++r) {
            float s = 0.f;
            #pragma unroll
            for (int nt = 0; nt < 8; ++nt) s += acc[nt][r] * wl[nt];
            p[tt][r] = s;
        }
    }
    #pragma unroll
    for (int tt = 0; tt < 8; ++tt)
        #pragma unroll
        for (int r = 0; r < 4; ++r) {
            float v = p[tt][r];
            v += __shfl_xor(v, 1, 64); v += __shfl_xor(v, 2, 64);
            v += __shfl_xor(v, 4, 64); v += __shfl_xor(v, 8, 64);
            p[tt][r] = v;
        }
    if (sl == 0) {
        #pragma unroll
        for (int r = 0; r < 4; ++r) {
            int row = row0 + wave * 16 + q * 4 + r;
            if (row < N) {
                #pragma unroll
                for (int tt = 0; tt < 8; ++tt)
                    out[(size_t)row * 8 + tt] = p[tt][r] + blin[tt];
            }
        }
    }
}

// ---------- launch ----------
extern "C" void kernel_launch(void* const* d_in, const int* in_sizes, int n_in,
                              void* d_out, int out_size, void* d_ws, size_t ws_size,
                              hipStream_t stream) {
    const float* x    = (const float*)d_in[0];
    const int*   ei   = (const int*)d_in[1];
    const float* ew   = (const float*)d_in[2];
    const float* W0   = (const float*)d_in[3];
    const float* Wih  = (const float*)d_in[4];
    const float* Whh  = (const float*)d_in[5];
    const float* bih  = (const float*)d_in[6];
    const float* bhh  = (const float*)d_in[7];
    const float* Wlin = (const float*)d_in[8];
    const float* blin = (const float*)d_in[9];
    int N = in_sizes[0] / F;   // 50000
    int E = in_sizes[1] / 2;   // 800000
    float* outp = (float*)d_out;

    int nblk = (N + 255) / 256;
    int cntBlocks = (E + 255) / 256;
    int M = N * 64;
    int M8 = N * 8;

    char* wsb = (char*)d_ws;
    size_t cur = 0;
    auto alloc = [&](size_t sz) -> void* {
        void* p = wsb + cur;
        cur = (cur + sz + 255) & ~(size_t)255;
        return p;
    };
    unsigned long long* packed8 = (unsigned long long*)alloc((size_t)M8 * 8);
    float* dinv = (float*)alloc((size_t)N * 4);
    int*   off  = (int*)  alloc((size_t)(N + 1) * 4);
    int*   bsum = (int*)  alloc((size_t)nblk * 4);
    int*   pos  = (int*)  alloc((size_t)E * 4);
    int*   copyBase = (int*)alloc((size_t)N * 8 * 4);
    int2*  ep   = (int2*) alloc((size_t)E * 8);
    unsigned short* Wth = (unsigned short*)alloc((size_t)F * F * 2);
    unsigned short* Wtl = (unsigned short*)alloc((size_t)F * F * 2);
    unsigned int* xs    = (unsigned int*)alloc((size_t)N * 64 * 4);
    unsigned int* hagg  = (unsigned int*)alloc((size_t)N * 64 * 4);
    (void)ws_size; (void)n_in; (void)out_size;

    hipMemsetAsync(packed8, 0, (size_t)M8 * 8, stream);
    hipLaunchKernelGGL(k_count_evolve, dim3(EVB + cntBlocks), dim3(256), 0, stream,
                       ei, ew, packed8, pos, E, N,
                       W0, Wih, Whh, bih, bhh, Wth, Wtl);
    hipLaunchKernelGGL(k_bsum, dim3(nblk), dim3(256), 0, stream, packed8, bsum, N);
    hipLaunchKernelGGL(k_offs, dim3(nblk), dim3(256), 0, stream,
                       packed8, bsum, off, copyBase, dinv, N, E, nblk);
    hipLaunchKernelGGL(k_place_cast, dim3(cntBlocks + (M + 255) / 256), dim3(256), 0, stream,
                       ei, ew, off, copyBase, pos, ep, E, cntBlocks,
                       (const float2*)x, dinv, xs, M);
    hipLaunchKernelGGL(k_agg2, dim3((N + 3) / 4), dim3(256), 0, stream,
                       (const uint4*)xs, off, ep, dinv, (uint4*)hagg, N);
    hipLaunchKernelGGL(k_gemm, dim3((N + 63) / 64), dim3(256), 0, stream,
                       (const uint4*)hagg, Wth, Wtl, Wlin, blin, outp, N);
}

// Round 8
// 216.676 us; speedup vs baseline: 1.3500x; 1.0054x over previous
//
#include <hip/hip_runtime.h>
#include <math.h>

#define F 128
#define FIX18     262144.0f            // 2^18 (deg fixed-point)
#define INV18     (1.0f / 262144.0f)
#define EVB 256                        // evolve blocks at front of count grid

using bf16x8 = __attribute__((ext_vector_type(8))) short;
using f32x4  = __attribute__((ext_vector_type(4))) float;

// ---------- helpers ----------
__device__ inline int read_idx(const int* ei, long long elem, int i64) {
    return i64 ? (int)((const long long*)ei)[elem] : ei[elem];
}
__device__ inline unsigned int f2bf_rn(float f) {   // fp32 -> bf16 bits, round-nearest-even
    unsigned int b = __float_as_uint(f);
    return (b + 0x7FFFu + ((b >> 16) & 1u)) >> 16;
}
__device__ inline float bflo(unsigned int u) { return __uint_as_float(u << 16); }
__device__ inline float bfhi(unsigned int u) { return __uint_as_float(u & 0xFFFF0000u); }

__device__ inline void acc8(float* acc, float wt, uint4 v) {
    acc[0] += wt * bflo(v.x); acc[1] += wt * bfhi(v.x);
    acc[2] += wt * bflo(v.y); acc[3] += wt * bfhi(v.y);
    acc[4] += wt * bflo(v.z); acc[5] += wt * bfhi(v.z);
    acc[6] += wt * bflo(v.w); acc[7] += wt * bfhi(v.w);
}

// per-block int64-dtype detection: first 32 column indices of an int64
// edge_index have all-zero high words.
__device__ inline int detect_i64(const int* ei, int* sh) {
    if (threadIdx.x == 0) {
        int i64 = 1;
        for (int j = 0; j < 32; ++j) if (ei[2 * j + 1] != 0) { i64 = 0; break; }
        *sh = i64;
    }
    __syncthreads();
    return *sh;
}

// ---------- K1: GRU evolve (blocks [0,EVB)) + XCD-privatized count atomics (rest) ----------
// 32-bit packed counter: [31:24]=count, [23:0]=sum(ew)*2^18.
// Per-copy count ~deg/8 (<=255 safe); per-copy weight-sum < 64 -> no bit overflow.
__global__ __launch_bounds__(256) void k_count_evolve(
        const int* __restrict__ ei, const float* __restrict__ ew,
        unsigned int* __restrict__ packed8, int* __restrict__ pos,
        int E, int N,
        const float* __restrict__ W0, const float* __restrict__ Wih,
        const float* __restrict__ Whh, const float* __restrict__ bih,
        const float* __restrict__ bhh,
        unsigned short* __restrict__ Wth, unsigned short* __restrict__ Wtl) {
    __shared__ int i64sh;
    int wave = threadIdx.x >> 6, lane = threadIdx.x & 63;
    if ((int)blockIdx.x >= EVB) {
        int i64 = detect_i64(ei, &i64sh);
        int e = ((int)blockIdx.x - EVB) * 256 + threadIdx.x;
        if (e >= E) return;
        int c = read_idx(ei, (long long)E + e, i64);
        unsigned int copy = blockIdx.x & 7;
        unsigned int u = (1u << 24) | (unsigned int)(ew[e] * FIX18 + 0.5f);
        unsigned int old = atomicAdd(&packed8[(size_t)copy * N + c], u);
        pos[e] = (int)((old >> 24) | (copy << 24));
        return;
    }
    // ---- evolve: wave gw handles pairs [gw*16, gw*16+16), lane = (slice<<4)|lp ----
    int gw = (int)blockIdx.x * 4 + wave;          // 0..1023
    int pairBase = gw * 16;
    int i = pairBase >> 7;                        // row of W0
    int jb = pairBase & 127;
    int lp = lane & 15, sl = lane >> 4;           // pair-in-wave, K-slice
    int j = jb + lp;                              // col of W
    const float* w0p = W0 + (size_t)i * F;
    const float* pir = Wih + (size_t)j * F;
    const float* piz = Wih + (size_t)(j + F) * F;
    const float* pin = Wih + (size_t)(j + 2 * F) * F;
    const float* phr = Whh + (size_t)j * F;
    const float* phz = Whh + (size_t)(j + F) * F;
    const float* phn = Whh + (size_t)(j + 2 * F) * F;
    float air = 0, aiz = 0, ain = 0, ahr = 0, ahz = 0, ahn = 0;
    int k0 = sl * 32;
    #pragma unroll
    for (int kk = 0; kk < 32; kk += 4) {
        int k = k0 + kk;
        float4 w0 = *(const float4*)&w0p[k];
        float4 a;
        a = *(const float4*)&pir[k]; air += w0.x*a.x + w0.y*a.y + w0.z*a.z + w0.w*a.w;
        a = *(const float4*)&piz[k]; aiz += w0.x*a.x + w0.y*a.y + w0.z*a.z + w0.w*a.w;
        a = *(const float4*)&pin[k]; ain += w0.x*a.x + w0.y*a.y + w0.z*a.z + w0.w*a.w;
        a = *(const float4*)&phr[k]; ahr += w0.x*a.x + w0.y*a.y + w0.z*a.z + w0.w*a.w;
        a = *(const float4*)&phz[k]; ahz += w0.x*a.x + w0.y*a.y + w0.z*a.z + w0.w*a.w;
        a = *(const float4*)&phn[k]; ahn += w0.x*a.x + w0.y*a.y + w0.z*a.z + w0.w*a.w;
    }
    air += __shfl_xor(air, 16, 64); air += __shfl_xor(air, 32, 64);
    aiz += __shfl_xor(aiz, 16, 64); aiz += __shfl_xor(aiz, 32, 64);
    ain += __shfl_xor(ain, 16, 64); ain += __shfl_xor(ain, 32, 64);
    ahr += __shfl_xor(ahr, 16, 64); ahr += __shfl_xor(ahr, 32, 64);
    ahz += __shfl_xor(ahz, 16, 64); ahz += __shfl_xor(ahz, 32, 64);
    ahn += __shfl_xor(ahn, 16, 64); ahn += __shfl_xor(ahn, 32, 64);
    if (sl == 0) {
        air += bih[j];          ahr += bhh[j];
        aiz += bih[j + F];      ahz += bhh[j + F];
        ain += bih[j + 2 * F];  ahn += bhh[j + 2 * F];
        float r = 1.0f / (1.0f + expf(-(air + ahr)));
        float z = 1.0f / (1.0f + expf(-(aiz + ahz)));
        float n = tanhf(ain + r * ahn);
        float w = (1.0f - z) * n + z * w0p[j];
        unsigned int hb = f2bf_rn(w);
        float whi = __uint_as_float(hb << 16);
        unsigned int lb = f2bf_rn(w - whi);
        Wth[j * F + i] = (unsigned short)hb;
        Wtl[j * F + i] = (unsigned short)lb;
    }
}

// ---------- K2: per-block sums of cnt (summed over 8 copies) ----------
__global__ void k_bsum(const unsigned int* __restrict__ packed8,
                       int* __restrict__ bsum, int N) {
    __shared__ int s[4];
    int i = blockIdx.x * 256 + threadIdx.x;
    int v = 0;
    if (i < N) {
        #pragma unroll
        for (int k = 0; k < 8; ++k)
            v += (int)(packed8[(size_t)k * N + i] >> 24);
    }
    #pragma unroll
    for (int o = 1; o < 64; o <<= 1) v += __shfl_xor(v, o, 64);
    if ((threadIdx.x & 63) == 0) s[threadIdx.x >> 6] = v;
    __syncthreads();
    if (threadIdx.x == 0) bsum[blockIdx.x] = s[0] + s[1] + s[2] + s[3];
}

// ---------- K3: offs (each block self-scans bsum; no separate bscan kernel) ----------
__global__ void k_offs(const unsigned int* __restrict__ packed8,
                       const int* __restrict__ bsum,
                       int* __restrict__ off, unsigned char* __restrict__ copyBase,
                       float* __restrict__ dinv, int N, int E, int nblk) {
    __shared__ int sdata[256];
    __shared__ int sred[4];
    __shared__ int sbase;
    int t = threadIdx.x;
    int b = blockIdx.x;
    int base = 0;
    for (int s0 = 0; s0 < nblk; s0 += 256) {
        int idx = s0 + t;
        int v = (idx < nblk && idx < b) ? bsum[idx] : 0;
        #pragma unroll
        for (int o = 1; o < 64; o <<= 1) v += __shfl_xor(v, o, 64);
        if ((t & 63) == 0) sred[t >> 6] = v;
        __syncthreads();
        if (t == 0) sbase = sred[0] + sred[1] + sred[2] + sred[3];
        __syncthreads();
        base += sbase;
        __syncthreads();
    }
    int i = b * 256 + t;
    int v = 0;
    unsigned int dsum = 0;
    if (i < N) {
        int run = 0;
        #pragma unroll
        for (int k = 0; k < 8; ++k) {
            unsigned int p = packed8[(size_t)k * N + i];
            copyBase[(size_t)i * 8 + k] = (unsigned char)run;
            run += (int)(p >> 24);
            dsum += (p & 0xFFFFFFu);
        }
        v = run;
    }
    sdata[t] = v;
    __syncthreads();
    #pragma unroll
    for (int s = 1; s < 256; s <<= 1) {
        int add = (t >= s) ? sdata[t - s] : 0;
        __syncthreads();
        sdata[t] += add;
        __syncthreads();
    }
    if (i < N) {
        off[i] = base + sdata[t] - v;  // exclusive CSR offset
        dinv[i] = rsqrtf(1.0f + (float)dsum * INV18);  // +1 self-loop
        if (i == N - 1) off[N] = E;
    }
}

// ---------- K4: edge placement (blocks [0,placeBlocks)) + xs cast (rest) ----------
__global__ __launch_bounds__(256) void k_place_cast(
        const int* __restrict__ ei, const float* __restrict__ ew,
        const int* __restrict__ off, const unsigned char* __restrict__ copyBase,
        const int* __restrict__ pos,
        int2* __restrict__ ep, int E, int placeBlocks,
        const float2* __restrict__ x2, const float* __restrict__ dinv,
        unsigned int* __restrict__ xs, int M) {
    __shared__ int i64sh;
    if ((int)blockIdx.x < placeBlocks) {
        int i64 = detect_i64(ei, &i64sh);
        int e = blockIdx.x * 256 + threadIdx.x;
        if (e >= E) return;
        int r = read_idx(ei, e, i64);
        int c = read_idx(ei, (long long)E + e, i64);
        unsigned int pe = (unsigned int)pos[e];
        int slot = off[c] + (int)copyBase[(size_t)c * 8 + (pe >> 24)] + (int)(pe & 0xFFFFFFu);
        ep[slot] = make_int2(r, __float_as_int(ew[e]));
    } else {
        int id = ((int)blockIdx.x - placeBlocks) * 256 + threadIdx.x;
        if (id >= M) return;
        float di = dinv[id >> 6];
        float2 v = x2[id];
        xs[id] = f2bf_rn(di * v.x) | (f2bf_rn(di * v.y) << 16);
    }
}

// ---------- K5: fused aggregation + MFMA GEMM + projection ----------
// 1024 threads = 16 waves; 64-node tile; each wave aggregates 4 nodes (16 edges
// in flight per node, same verified k_agg2 inner loop) into the LDS A-tile.
// After barrier, waves 0-3 run the verified 4-wave gemm; waves 4-15 return.
__global__ __launch_bounds__(1024) void k_agg_gemm(
        const uint4* __restrict__ xs4, const int* __restrict__ off,
        const int2* __restrict__ ep, const float* __restrict__ dinv,
        const unsigned short* __restrict__ Wth, const unsigned short* __restrict__ Wtl,
        const float* __restrict__ Wlin, const float* __restrict__ blin,
        float* __restrict__ out, int N) {
    __shared__ __align__(16) unsigned int At[64 * 68];  // 64 rows bf16x128, stride 68 uints
    __shared__ __align__(16) float WlinL[8 * F];
    int t = threadIdx.x;
    int wave = t >> 6, lane = t & 63;
    int row0 = blockIdx.x * 64;
    WlinL[t] = Wlin[t];                   // 1024 floats
    int g = lane >> 4, sl = lane & 15;

    // ---- aggregation: wave handles rows [wave*4, wave*4+4) ----
    #pragma unroll
    for (int sub = 0; sub < 4; ++sub) {
        int rr = wave * 4 + sub;
        int c = row0 + rr;
        if (c < N) {
            int start = off[c], end = off[c + 1];
            float di = dinv[c];
            float a0[8] = {0,0,0,0,0,0,0,0}, a1[8] = {0,0,0,0,0,0,0,0};
            if (g == 0) {   // self-loop (raw weight 1)
                uint4 v = xs4[(size_t)c * 16 + sl];
                a0[0] = bflo(v.x); a0[1] = bfhi(v.x);
                a0[2] = bflo(v.y); a0[3] = bfhi(v.y);
                a0[4] = bflo(v.z); a0[5] = bfhi(v.z);
                a0[6] = bflo(v.w); a0[7] = bfhi(v.w);
            }
            int last = end - 1;
            for (int k = start; k < end; k += 16) {
                int iA = k + g, iB = k + g + 4, iC = k + g + 8, iD = k + g + 12;
                int2 eA = ep[min(iA, last)];
                int2 eB = ep[min(iB, last)];
                int2 eC = ep[min(iC, last)];
                int2 eD = ep[min(iD, last)];
                uint4 vA = xs4[(size_t)eA.x * 16 + sl];
                uint4 vB = xs4[(size_t)eB.x * 16 + sl];
                uint4 vC = xs4[(size_t)eC.x * 16 + sl];
                uint4 vD = xs4[(size_t)eD.x * 16 + sl];
                float wA = (iA <= last) ? __int_as_float(eA.y) : 0.f;
                float wB = (iB <= last) ? __int_as_float(eB.y) : 0.f;
                float wC = (iC <= last) ? __int_as_float(eC.y) : 0.f;
                float wD = (iD <= last) ? __int_as_float(eD.y) : 0.f;
                acc8(a0, wA, vA);
                acc8(a1, wB, vB);
                acc8(a0, wC, vC);
                acc8(a1, wD, vD);
            }
            #pragma unroll
            for (int f = 0; f < 8; ++f) {
                float v = a0[f] + a1[f];
                v += __shfl_xor(v, 16, 64);
                v += __shfl_xor(v, 32, 64);
                a0[f] = v;
            }
            if (lane < 16) {
                uint4 o;
                o.x = f2bf_rn(di * a0[0]) | (f2bf_rn(di * a0[1]) << 16);
                o.y = f2bf_rn(di * a0[2]) | (f2bf_rn(di * a0[3]) << 16);
                o.z = f2bf_rn(di * a0[4]) | (f2bf_rn(di * a0[5]) << 16);
                o.w = f2bf_rn(di * a0[6]) | (f2bf_rn(di * a0[7]) << 16);
                *(uint4*)&At[rr * 68 + sl * 4] = o;
            }
        } else if (lane < 16) {
            *(uint4*)&At[rr * 68 + sl * 4] = make_uint4(0u, 0u, 0u, 0u);
        }
    }
    __syncthreads();
    if (wave >= 4) return;

    // ---- gemm: waves 0-3, verified 4-wave body ----
    int q = g;
    const unsigned short* Ash = (const unsigned short*)At;
    int mrow = wave * 16 + sl;
    f32x4 acc[8];
    #pragma unroll
    for (int nt = 0; nt < 8; ++nt) acc[nt] = (f32x4){0.f, 0.f, 0.f, 0.f};
    #pragma unroll
    for (int ko = 0; ko < 4; ++ko) {
        bf16x8 a = *(const bf16x8*)&Ash[mrow * 136 + ko * 32 + q * 8];
        #pragma unroll
        for (int nt = 0; nt < 8; ++nt) {
            int boff = (nt * 16 + sl) * F + ko * 32 + q * 8;
            bf16x8 bh = *(const bf16x8*)&Wth[boff];
            bf16x8 bl = *(const bf16x8*)&Wtl[boff];
            acc[nt] = __builtin_amdgcn_mfma_f32_16x16x32_bf16(a, bh, acc[nt], 0, 0, 0);
            acc[nt] = __builtin_amdgcn_mfma_f32_16x16x32_bf16(a, bl, acc[nt], 0, 0, 0);
        }
    }
    #pragma unroll
    for (int nt = 0; nt < 8; ++nt)
        #pragma unroll
        for (int r = 0; r < 4; ++r) acc[nt][r] = fmaxf(acc[nt][r], 0.f);

    float p[8][4];
    #pragma unroll
    for (int tt = 0; tt < 8; ++tt) {
        float wl[8];
        #pragma unroll
        for (int nt = 0; nt < 8; ++nt) wl[nt] = WlinL[tt * F + nt * 16 + sl];
        #pragma unroll
        for (int r = 0; r < 4; ++r) {
            float s = 0.f;
            #pragma unroll
            for (int nt = 0; nt < 8; ++nt) s += acc[nt][r] * wl[nt];
            p[tt][r] = s;
        }
    }
    #pragma unroll
    for (int tt = 0; tt < 8; ++tt)
        #pragma unroll
        for (int r = 0; r < 4; ++r) {
            float v = p[tt][r];
            v += __shfl_xor(v, 1, 64); v += __shfl_xor(v, 2, 64);
            v += __shfl_xor(v, 4, 64); v += __shfl_xor(v, 8, 64);
            p[tt][r] = v;
        }
    if (sl == 0) {
        #pragma unroll
        for (int r = 0; r < 4; ++r) {
            int row = row0 + wave * 16 + q * 4 + r;
            if (row < N) {
                #pragma unroll
                for (int tt = 0; tt < 8; ++tt)
                    out[(size_t)row * 8 + tt] = p[tt][r] + blin[tt];
            }
        }
    }
}

// ---------- launch ----------
extern "C" void kernel_launch(void* const* d_in, const int* in_sizes, int n_in,
                              void* d_out, int out_size, void* d_ws, size_t ws_size,
                              hipStream_t stream) {
    const float* x    = (const float*)d_in[0];
    const int*   ei   = (const int*)d_in[1];
    const float* ew   = (const float*)d_in[2];
    const float* W0   = (const float*)d_in[3];
    const float* Wih  = (const float*)d_in[4];
    const float* Whh  = (const float*)d_in[5];
    const float* bih  = (const float*)d_in[6];
    const float* bhh  = (const float*)d_in[7];
    const float* Wlin = (const float*)d_in[8];
    const float* blin = (const float*)d_in[9];
    int N = in_sizes[0] / F;   // 50000
    int E = in_sizes[1] / 2;   // 800000
    float* outp = (float*)d_out;

    int nblk = (N + 255) / 256;
    int cntBlocks = (E + 255) / 256;
    int M = N * 64;

    char* wsb = (char*)d_ws;
    size_t cur = 0;
    auto alloc = [&](size_t sz) -> void* {
        void* p = wsb + cur;
        cur = (cur + sz + 255) & ~(size_t)255;
        return p;
    };
    unsigned int* packed8 = (unsigned int*)alloc((size_t)N * 8 * 4);
    float* dinv = (float*)alloc((size_t)N * 4);
    int*   off  = (int*)  alloc((size_t)(N + 1) * 4);
    int*   bsum = (int*)  alloc((size_t)nblk * 4);
    int*   pos  = (int*)  alloc((size_t)E * 4);
    unsigned char* copyBase = (unsigned char*)alloc((size_t)N * 8);
    int2*  ep   = (int2*) alloc((size_t)E * 8);
    unsigned short* Wth = (unsigned short*)alloc((size_t)F * F * 2);
    unsigned short* Wtl = (unsigned short*)alloc((size_t)F * F * 2);
    unsigned int* xs    = (unsigned int*)alloc((size_t)N * 64 * 4);
    (void)ws_size; (void)n_in; (void)out_size;

    hipMemsetAsync(packed8, 0, (size_t)N * 8 * 4, stream);
    hipLaunchKernelGGL(k_count_evolve, dim3(EVB + cntBlocks), dim3(256), 0, stream,
                       ei, ew, packed8, pos, E, N,
                       W0, Wih, Whh, bih, bhh, Wth, Wtl);
    hipLaunchKernelGGL(k_bsum, dim3(nblk), dim3(256), 0, stream, packed8, bsum, N);
    hipLaunchKernelGGL(k_offs, dim3(nblk), dim3(256), 0, stream,
                       packed8, bsum, off, copyBase, dinv, N, E, nblk);
    hipLaunchKernelGGL(k_place_cast, dim3(cntBlocks + (M + 255) / 256), dim3(256), 0, stream,
                       ei, ew, off, copyBase, pos, ep, E, cntBlocks,
                       (const float2*)x, dinv, xs, M);
    hipLaunchKernelGGL(k_agg_gemm, dim3((N + 63) / 64), dim3(1024), 0, stream,
                       (const uint4*)xs, off, ep, dinv, Wth, Wtl, Wlin, blin, outp, N);
}

// Round 9
// 212.521 us; speedup vs baseline: 1.3764x; 1.0196x over previous
//
#include <hip/hip_runtime.h>
#include <math.h>

#define F 128
#define FIX18     262144.0f            // 2^18 (deg fixed-point)
#define INV18     (1.0f / 262144.0f)
#define EVB 256                        // evolve blocks at front of count grid

using bf16x8 = __attribute__((ext_vector_type(8))) short;
using f32x4  = __attribute__((ext_vector_type(4))) float;

// ---------- helpers ----------
__device__ inline int read_idx(const int* ei, long long elem, int i64) {
    return i64 ? (int)((const long long*)ei)[elem] : ei[elem];
}
__device__ inline unsigned int f2bf_rn(float f) {   // fp32 -> bf16 bits, round-nearest-even
    unsigned int b = __float_as_uint(f);
    return (b + 0x7FFFu + ((b >> 16) & 1u)) >> 16;
}
__device__ inline float bflo(unsigned int u) { return __uint_as_float(u << 16); }
__device__ inline float bfhi(unsigned int u) { return __uint_as_float(u & 0xFFFF0000u); }

__device__ inline void acc8(float* acc, float wt, uint4 v) {
    acc[0] += wt * bflo(v.x); acc[1] += wt * bfhi(v.x);
    acc[2] += wt * bflo(v.y); acc[3] += wt * bfhi(v.y);
    acc[4] += wt * bflo(v.z); acc[5] += wt * bfhi(v.z);
    acc[6] += wt * bflo(v.w); acc[7] += wt * bfhi(v.w);
}

// per-block int64-dtype detection: first 32 column indices of an int64
// edge_index have all-zero high words.
__device__ inline int detect_i64(const int* ei, int* sh) {
    if (threadIdx.x == 0) {
        int i64 = 1;
        for (int j = 0; j < 32; ++j) if (ei[2 * j + 1] != 0) { i64 = 0; break; }
        *sh = i64;
    }
    __syncthreads();
    return *sh;
}

// ---------- K1: GRU evolve (blocks [0,EVB)) + XCD-privatized count atomics (rest) ----------
// 32-bit packed counter: [31:24]=count, [23:0]=sum(ew)*2^18.
__global__ __launch_bounds__(256) void k_count_evolve(
        const int* __restrict__ ei, const float* __restrict__ ew,
        unsigned int* __restrict__ packed8, int* __restrict__ pos,
        int E, int N,
        const float* __restrict__ W0, const float* __restrict__ Wih,
        const float* __restrict__ Whh, const float* __restrict__ bih,
        const float* __restrict__ bhh,
        unsigned short* __restrict__ Wth, unsigned short* __restrict__ Wtl) {
    __shared__ int i64sh;
    int wave = threadIdx.x >> 6, lane = threadIdx.x & 63;
    if ((int)blockIdx.x >= EVB) {
        int i64 = detect_i64(ei, &i64sh);
        int e = ((int)blockIdx.x - EVB) * 256 + threadIdx.x;
        if (e >= E) return;
        int c = read_idx(ei, (long long)E + e, i64);
        unsigned int copy = blockIdx.x & 7;
        unsigned int u = (1u << 24) | (unsigned int)(ew[e] * FIX18 + 0.5f);
        unsigned int old = atomicAdd(&packed8[(size_t)copy * N + c], u);
        pos[e] = (int)((old >> 24) | (copy << 24));
        return;
    }
    // ---- evolve: wave gw handles pairs [gw*16, gw*16+16), lane = (slice<<4)|lp ----
    int gw = (int)blockIdx.x * 4 + wave;          // 0..1023
    int pairBase = gw * 16;
    int i = pairBase >> 7;                        // row of W0
    int jb = pairBase & 127;
    int lp = lane & 15, sl = lane >> 4;           // pair-in-wave, K-slice
    int j = jb + lp;                              // col of W
    const float* w0p = W0 + (size_t)i * F;
    const float* pir = Wih + (size_t)j * F;
    const float* piz = Wih + (size_t)(j + F) * F;
    const float* pin = Wih + (size_t)(j + 2 * F) * F;
    const float* phr = Whh + (size_t)j * F;
    const float* phz = Whh + (size_t)(j + F) * F;
    const float* phn = Whh + (size_t)(j + 2 * F) * F;
    float air = 0, aiz = 0, ain = 0, ahr = 0, ahz = 0, ahn = 0;
    int k0 = sl * 32;
    #pragma unroll
    for (int kk = 0; kk < 32; kk += 4) {
        int k = k0 + kk;
        float4 w0 = *(const float4*)&w0p[k];
        float4 a;
        a = *(const float4*)&pir[k]; air += w0.x*a.x + w0.y*a.y + w0.z*a.z + w0.w*a.w;
        a = *(const float4*)&piz[k]; aiz += w0.x*a.x + w0.y*a.y + w0.z*a.z + w0.w*a.w;
        a = *(const float4*)&pin[k]; ain += w0.x*a.x + w0.y*a.y + w0.z*a.z + w0.w*a.w;
        a = *(const float4*)&phr[k]; ahr += w0.x*a.x + w0.y*a.y + w0.z*a.z + w0.w*a.w;
        a = *(const float4*)&phz[k]; ahz += w0.x*a.x + w0.y*a.y + w0.z*a.z + w0.w*a.w;
        a = *(const float4*)&phn[k]; ahn += w0.x*a.x + w0.y*a.y + w0.z*a.z + w0.w*a.w;
    }
    air += __shfl_xor(air, 16, 64); air += __shfl_xor(air, 32, 64);
    aiz += __shfl_xor(aiz, 16, 64); aiz += __shfl_xor(aiz, 32, 64);
    ain += __shfl_xor(ain, 16, 64); ain += __shfl_xor(ain, 32, 64);
    ahr += __shfl_xor(ahr, 16, 64); ahr += __shfl_xor(ahr, 32, 64);
    ahz += __shfl_xor(ahz, 16, 64); ahz += __shfl_xor(ahz, 32, 64);
    ahn += __shfl_xor(ahn, 16, 64); ahn += __shfl_xor(ahn, 32, 64);
    if (sl == 0) {
        air += bih[j];          ahr += bhh[j];
        aiz += bih[j + F];      ahz += bhh[j + F];
        ain += bih[j + 2 * F];  ahn += bhh[j + 2 * F];
        float r = 1.0f / (1.0f + expf(-(air + ahr)));
        float z = 1.0f / (1.0f + expf(-(aiz + ahz)));
        float n = tanhf(ain + r * ahn);
        float w = (1.0f - z) * n + z * w0p[j];
        unsigned int hb = f2bf_rn(w);
        float whi = __uint_as_float(hb << 16);
        unsigned int lb = f2bf_rn(w - whi);
        Wth[j * F + i] = (unsigned short)hb;
        Wtl[j * F + i] = (unsigned short)lb;
    }
}

// ---------- K2: per-block sums of cnt (summed over 8 copies) ----------
__global__ void k_bsum(const unsigned int* __restrict__ packed8,
                       int* __restrict__ bsum, int N) {
    __shared__ int s[4];
    int i = blockIdx.x * 256 + threadIdx.x;
    int v = 0;
    if (i < N) {
        #pragma unroll
        for (int k = 0; k < 8; ++k)
            v += (int)(packed8[(size_t)k * N + i] >> 24);
    }
    #pragma unroll
    for (int o = 1; o < 64; o <<= 1) v += __shfl_xor(v, o, 64);
    if ((threadIdx.x & 63) == 0) s[threadIdx.x >> 6] = v;
    __syncthreads();
    if (threadIdx.x == 0) bsum[blockIdx.x] = s[0] + s[1] + s[2] + s[3];
}

// ---------- K3: offs (each block self-scans bsum; no separate bscan kernel) ----------
__global__ void k_offs(const unsigned int* __restrict__ packed8,
                       const int* __restrict__ bsum,
                       int* __restrict__ off, unsigned char* __restrict__ copyBase,
                       float* __restrict__ dinv, int N, int E, int nblk) {
    __shared__ int sdata[256];
    __shared__ int sred[4];
    __shared__ int sbase;
    int t = threadIdx.x;
    int b = blockIdx.x;
    int base = 0;
    for (int s0 = 0; s0 < nblk; s0 += 256) {
        int idx = s0 + t;
        int v = (idx < nblk && idx < b) ? bsum[idx] : 0;
        #pragma unroll
        for (int o = 1; o < 64; o <<= 1) v += __shfl_xor(v, o, 64);
        if ((t & 63) == 0) sred[t >> 6] = v;
        __syncthreads();
        if (t == 0) sbase = sred[0] + sred[1] + sred[2] + sred[3];
        __syncthreads();
        base += sbase;
        __syncthreads();
    }
    int i = b * 256 + t;
    int v = 0;
    unsigned int dsum = 0;
    if (i < N) {
        int run = 0;
        #pragma unroll
        for (int k = 0; k < 8; ++k) {
            unsigned int p = packed8[(size_t)k * N + i];
            copyBase[(size_t)i * 8 + k] = (unsigned char)run;
            run += (int)(p >> 24);
            dsum += (p & 0xFFFFFFu);
        }
        v = run;
    }
    sdata[t] = v;
    __syncthreads();
    #pragma unroll
    for (int s = 1; s < 256; s <<= 1) {
        int add = (t >= s) ? sdata[t - s] : 0;
        __syncthreads();
        sdata[t] += add;
        __syncthreads();
    }
    if (i < N) {
        off[i] = base + sdata[t] - v;  // exclusive CSR offset
        dinv[i] = rsqrtf(1.0f + (float)dsum * INV18);  // +1 self-loop
        if (i == N - 1) off[N] = E;
    }
}

// ---------- K4: edge placement (blocks [0,placeBlocks)) + xs cast (rest) ----------
__global__ __launch_bounds__(256) void k_place_cast(
        const int* __restrict__ ei, const float* __restrict__ ew,
        const int* __restrict__ off, const unsigned char* __restrict__ copyBase,
        const int* __restrict__ pos,
        int2* __restrict__ ep, int E, int placeBlocks,
        const float2* __restrict__ x2, const float* __restrict__ dinv,
        unsigned int* __restrict__ xs, int M) {
    __shared__ int i64sh;
    if ((int)blockIdx.x < placeBlocks) {
        int i64 = detect_i64(ei, &i64sh);
        int e = blockIdx.x * 256 + threadIdx.x;
        if (e >= E) return;
        int r = read_idx(ei, e, i64);
        int c = read_idx(ei, (long long)E + e, i64);
        unsigned int pe = (unsigned int)pos[e];
        int slot = off[c] + (int)copyBase[(size_t)c * 8 + (pe >> 24)] + (int)(pe & 0xFFFFFFu);
        ep[slot] = make_int2(r, __float_as_int(ew[e]));
    } else {
        int id = ((int)blockIdx.x - placeBlocks) * 256 + threadIdx.x;
        if (id >= M) return;
        float di = dinv[id >> 6];
        float2 v = x2[id];
        xs[id] = f2bf_rn(di * v.x) | (f2bf_rn(di * v.y) << 16);
    }
}

// ---------- K5: aggregation: hagg[c] = bf16( dinv[c] * (xs[c] + sum ew*xs[r]) ) ----------
// One node per wave; 16 edges/iteration (4 per 16-lane group), branchless tail via
// index clamp + zero weight so all 4 gathers issue unconditionally (deep MLP).
__global__ __launch_bounds__(256) void k_agg2(const uint4* __restrict__ xs4,
                                              const int* __restrict__ off,
                                              const int2* __restrict__ ep,
                                              const float* __restrict__ dinv,
                                              uint4* __restrict__ hagg4, int N) {
    int wave = threadIdx.x >> 6, lane = threadIdx.x & 63;
    int c = blockIdx.x * 4 + wave;
    if (c >= N) return;
    int g = lane >> 4, sl = lane & 15;
    int start = off[c], end = off[c + 1];
    float di = dinv[c];
    float a0[8] = {0,0,0,0,0,0,0,0}, a1[8] = {0,0,0,0,0,0,0,0};
    if (g == 0) {   // self-loop (raw weight 1)
        uint4 v = xs4[(size_t)c * 16 + sl];
        a0[0] = bflo(v.x); a0[1] = bfhi(v.x);
        a0[2] = bflo(v.y); a0[3] = bfhi(v.y);
        a0[4] = bflo(v.z); a0[5] = bfhi(v.z);
        a0[6] = bflo(v.w); a0[7] = bfhi(v.w);
    }
    int last = end - 1;
    for (int k = start; k < end; k += 16) {
        int iA = k + g, iB = k + g + 4, iC = k + g + 8, iD = k + g + 12;
        int2 eA = ep[min(iA, last)];
        int2 eB = ep[min(iB, last)];
        int2 eC = ep[min(iC, last)];
        int2 eD = ep[min(iD, last)];
        uint4 vA = xs4[(size_t)eA.x * 16 + sl];
        uint4 vB = xs4[(size_t)eB.x * 16 + sl];
        uint4 vC = xs4[(size_t)eC.x * 16 + sl];
        uint4 vD = xs4[(size_t)eD.x * 16 + sl];
        float wA = (iA <= last) ? __int_as_float(eA.y) : 0.f;
        float wB = (iB <= last) ? __int_as_float(eB.y) : 0.f;
        float wC = (iC <= last) ? __int_as_float(eC.y) : 0.f;
        float wD = (iD <= last) ? __int_as_float(eD.y) : 0.f;
        acc8(a0, wA, vA);
        acc8(a1, wB, vB);
        acc8(a0, wC, vC);
        acc8(a1, wD, vD);
    }
    #pragma unroll
    for (int f = 0; f < 8; ++f) {
        float v = a0[f] + a1[f];
        v += __shfl_xor(v, 16, 64);
        v += __shfl_xor(v, 32, 64);
        a0[f] = v;
    }
    if (lane < 16) {
        uint4 o;
        o.x = f2bf_rn(di * a0[0]) | (f2bf_rn(di * a0[1]) << 16);
        o.y = f2bf_rn(di * a0[2]) | (f2bf_rn(di * a0[3]) << 16);
        o.z = f2bf_rn(di * a0[4]) | (f2bf_rn(di * a0[5]) << 16);
        o.w = f2bf_rn(di * a0[6]) | (f2bf_rn(di * a0[7]) << 16);
        hagg4[(size_t)c * 16 + lane] = o;
    }
}

// ---------- K6: out = relu(hagg @ W) @ Wlin^T + blin  (MFMA, split-bf16 W) ----------
__global__ __launch_bounds__(256) void k_gemm(const uint4* __restrict__ hagg4,
                                              const unsigned short* __restrict__ Wth,
                                              const unsigned short* __restrict__ Wtl,
                                              const float* __restrict__ Wlin,
                                              const float* __restrict__ blin,
                                              float* __restrict__ out, int N) {
    __shared__ __align__(16) unsigned int At[64 * 68];  // 64 rows bf16x128, stride padded 68 uints
    __shared__ __align__(16) float WlinL[8 * F];
    int t = threadIdx.x;
    int row0 = blockIdx.x * 64;
    #pragma unroll
    for (int it = 0; it < 4; ++it) {
        int idx = it * 256 + t;          // 1024 uint4 slots
        int rr = idx >> 4, c4 = idx & 15;
        uint4 v = make_uint4(0u, 0u, 0u, 0u);
        if (row0 + rr < N) v = hagg4[(size_t)(row0 + rr) * 16 + c4];
        *(uint4*)&At[rr * 68 + c4 * 4] = v;
    }
    *(float4*)&WlinL[t * 4] = *(const float4*)&Wlin[t * 4];   // 1024 floats
    __syncthreads();

    int wave = t >> 6, lane = t & 63;
    int sl = lane & 15, q = lane >> 4;
    const unsigned short* Ash = (const unsigned short*)At;
    int mrow = wave * 16 + sl;           // A-row within tile (m = lane&15)

    f32x4 acc[8];
    #pragma unroll
    for (int nt = 0; nt < 8; ++nt) acc[nt] = (f32x4){0.f, 0.f, 0.f, 0.f};
    #pragma unroll
    for (int ko = 0; ko < 4; ++ko) {
        bf16x8 a = *(const bf16x8*)&Ash[mrow * 136 + ko * 32 + q * 8];
        #pragma unroll
        for (int nt = 0; nt < 8; ++nt) {
            int boff = (nt * 16 + sl) * F + ko * 32 + q * 8;
            bf16x8 bh = *(const bf16x8*)&Wth[boff];
            bf16x8 bl = *(const bf16x8*)&Wtl[boff];
            acc[nt] = __builtin_amdgcn_mfma_f32_16x16x32_bf16(a, bh, acc[nt], 0, 0, 0);
            acc[nt] = __builtin_amdgcn_mfma_f32_16x16x32_bf16(a, bl, acc[nt], 0, 0, 0);
        }
    }
    // relu (C layout: row = q*4+reg, col = nt*16+sl)
    #pragma unroll
    for (int nt = 0; nt < 8; ++nt)
        #pragma unroll
        for (int r = 0; r < 4; ++r) acc[nt][r] = fmaxf(acc[nt][r], 0.f);

    // fp32 projection: p[t][reg] = sum_col relu(S)[row][col] * Wlin[t][col]
    float p[8][4];
    #pragma unroll
    for (int tt = 0; tt < 8; ++tt) {
        float wl[8];
        #pragma unroll
        for (int nt = 0; nt < 8; ++nt) wl[nt] = WlinL[tt * F + nt * 16 + sl];
        #pragma unroll
        for (int r = 0; r < 4; ++r) {
            float s = 0.f;
            #pragma unroll
            for (int nt = 0; nt < 8; ++nt) s += acc[nt][r] * wl[nt];
            p[tt][r] = s;
        }
    }
    #pragma unroll
    for (int tt = 0; tt < 8; ++tt)
        #pragma unroll
        for (int r = 0; r < 4; ++r) {
            float v = p[tt][r];
            v += __shfl_xor(v, 1, 64); v += __shfl_xor(v, 2, 64);
            v += __shfl_xor(v, 4, 64); v += __shfl_xor(v, 8, 64);
            p[tt][r] = v;
        }
    if (sl == 0) {
        #pragma unroll
        for (int r = 0; r < 4; ++r) {
            int row = row0 + wave * 16 + q * 4 + r;
            if (row < N) {
                #pragma unroll
                for (int tt = 0; tt < 8; ++tt)
                    out[(size_t)row * 8 + tt] = p[tt][r] + blin[tt];
            }
        }
    }
}

// ---------- launch ----------
extern "C" void kernel_launch(void* const* d_in, const int* in_sizes, int n_in,
                              void* d_out, int out_size, void* d_ws, size_t ws_size,
                              hipStream_t stream) {
    const float* x    = (const float*)d_in[0];
    const int*   ei   = (const int*)d_in[1];
    const float* ew   = (const float*)d_in[2];
    const float* W0   = (const float*)d_in[3];
    const float* Wih  = (const float*)d_in[4];
    const float* Whh  = (const float*)d_in[5];
    const float* bih  = (const float*)d_in[6];
    const float* bhh  = (const float*)d_in[7];
    const float* Wlin = (const float*)d_in[8];
    const float* blin = (const float*)d_in[9];
    int N = in_sizes[0] / F;   // 50000
    int E = in_sizes[1] / 2;   // 800000
    float* outp = (float*)d_out;

    int nblk = (N + 255) / 256;
    int cntBlocks = (E + 255) / 256;
    int M = N * 64;

    char* wsb = (char*)d_ws;
    size_t cur = 0;
    auto alloc = [&](size_t sz) -> void* {
        void* p = wsb + cur;
        cur = (cur + sz + 255) & ~(size_t)255;
        return p;
    };
    unsigned int* packed8 = (unsigned int*)alloc((size_t)N * 8 * 4);
    float* dinv = (float*)alloc((size_t)N * 4);
    int*   off  = (int*)  alloc((size_t)(N + 1) * 4);
    int*   bsum = (int*)  alloc((size_t)nblk * 4);
    int*   pos  = (int*)  alloc((size_t)E * 4);
    unsigned char* copyBase = (unsigned char*)alloc((size_t)N * 8);
    int2*  ep   = (int2*) alloc((size_t)E * 8);
    unsigned short* Wth = (unsigned short*)alloc((size_t)F * F * 2);
    unsigned short* Wtl = (unsigned short*)alloc((size_t)F * F * 2);
    unsigned int* xs    = (unsigned int*)alloc((size_t)N * 64 * 4);
    unsigned int* hagg  = (unsigned int*)alloc((size_t)N * 64 * 4);
    (void)ws_size; (void)n_in; (void)out_size;

    hipMemsetAsync(packed8, 0, (size_t)N * 8 * 4, stream);
    hipLaunchKernelGGL(k_count_evolve, dim3(EVB + cntBlocks), dim3(256), 0, stream,
                       ei, ew, packed8, pos, E, N,
                       W0, Wih, Whh, bih, bhh, Wth, Wtl);
    hipLaunchKernelGGL(k_bsum, dim3(nblk), dim3(256), 0, stream, packed8, bsum, N);
    hipLaunchKernelGGL(k_offs, dim3(nblk), dim3(256), 0, stream,
                       packed8, bsum, off, copyBase, dinv, N, E, nblk);
    hipLaunchKernelGGL(k_place_cast, dim3(cntBlocks + (M + 255) / 256), dim3(256), 0, stream,
                       ei, ew, off, copyBase, pos, ep, E, cntBlocks,
                       (const float2*)x, dinv, xs, M);
    hipLaunchKernelGGL(k_agg2, dim3((N + 3) / 4), dim3(256), 0, stream,
                       (const uint4*)xs, off, ep, dinv, (uint4*)hagg, N);
    hipLaunchKernelGGL(k_gemm, dim3((N + 63) / 64), dim3(256), 0, stream,
                       (const uint4*)hagg, Wth, Wtl, Wlin, blin, outp, N);
}